// Round 2
// 959.135 us; speedup vs baseline: 1.1717x; 1.1717x over previous
//
#include <hip/hip_runtime.h>
#include <stdint.h>
#include <stddef.h>

// Problem: out = x @ base_kernel + bias + 2.0 * (x @ kron(lora_A@lora_B, O))
// Folded:  out = x @ (base_kernel + 2.0*kron(A@B, O)) + bias  -- ONE bf16 GEMM.
// x: (16384 x 4096) f32, W: (4096 x 4096) f32, out f32.
//
// R2: identical to R1 (256^2 tile, BK=64, 8 waves, counted-vmcnt pipeline, LDS
// XOR-swizzle via pre-swizzled global src, setprio, XCD swizzle) EXCEPT the
// barrier is hardened: raw s_barrier is now bracketed by "memory"-clobbered asm
// on BOTH sides so ds_reads cannot hoist above the barrier (LLVM does not model
// s_barrier as a memory fence; guide rule 18 / 8-phase template place the fence
// after the barrier).

#define M_TOT 16384
#define K_TOT 4096
#define N_TOT 4096
#define SCALING 2.0f
#define NT (K_TOT / 64)   // 64 K-tiles of BK=64 (two 32-wide k-subtiles each)

typedef __attribute__((ext_vector_type(8))) short bf16x8;   // 8 bf16 = 4 VGPRs (MFMA A/B frag)
typedef __attribute__((ext_vector_type(4))) float floatx4;  // MFMA C/D frag

__device__ __forceinline__ unsigned short f32_to_bf16(float f) {
  union { float f; unsigned int u; } v; v.f = f;
  unsigned int r = 0x7fffu + ((v.u >> 16) & 1u);  // round-to-nearest-even
  return (unsigned short)((v.u + r) >> 16);
}

// 16-byte async global->LDS copy (global_load_lds_dwordx4).
// HW semantics: LDS dest = wave-uniform base + lane*16 -- all layouts below keep the
// LDS destination lane-linear and put the swizzle in the GLOBAL source address.
__device__ __forceinline__ void async_copy16(const void* gsrc, void* ldst) {
  __builtin_amdgcn_global_load_lds(
      (const __attribute__((address_space(1))) void*)(uintptr_t)gsrc,
      (__attribute__((address_space(3))) void*)(uintptr_t)ldst,
      16, 0, 0);
}

// ---- Kernel 1: wl = SCALING * (lora_A @ lora_B), 16x16, fp32 ----
__global__ void wleft_kernel(const float* __restrict__ A, const float* __restrict__ B,
                             float* __restrict__ wl) {
  int i = threadIdx.x >> 4, j = threadIdx.x & 15;
  float s = 0.f;
#pragma unroll
  for (int k = 0; k < 16; ++k) s += A[i * 16 + k] * B[k * 16 + j];
  wl[threadIdx.x] = s * SCALING;
}

// ---- Kernel 2: Wt[n][k] = bf16( base[k][n] + wl[k>>8][n>>8] * O[k&255][n&255] ) ----
__global__ void prep_w_kernel(const float* __restrict__ base, const float* __restrict__ O,
                              const float* __restrict__ wl, unsigned short* __restrict__ Wt) {
  __shared__ float tile[32][33];  // +1 pad: bank-conflict-free transpose
  int n0 = blockIdx.x * 32, k0 = blockIdx.y * 32;
  int tx = threadIdx.x, ty = threadIdx.y;  // (32, 8)
#pragma unroll
  for (int r = 0; r < 32; r += 8) {
    int k = k0 + ty + r, n = n0 + tx;
    float v = base[(size_t)k * N_TOT + n]
            + wl[((k >> 8) << 4) + (n >> 8)] * O[((size_t)(k & 255) << 8) + (n & 255)];
    tile[ty + r][tx] = v;
  }
  __syncthreads();
#pragma unroll
  for (int r = 0; r < 32; r += 8) {
    int n = n0 + ty + r, k = k0 + tx;
    Wt[(size_t)n * K_TOT + k] = f32_to_bf16(tile[tx][ty + r]);
  }
}

// ---- Kernel 3: x f32 -> bf16, 8 elems/thread ----
__global__ void cvt_x_kernel(const float* __restrict__ x, unsigned short* __restrict__ xb) {
  size_t i = ((size_t)blockIdx.x * blockDim.x + threadIdx.x) * 8;
  float4 a = *(const float4*)(x + i);
  float4 b = *(const float4*)(x + i + 4);
  union { bf16x8 v; unsigned short h[8]; } u;
  u.h[0] = f32_to_bf16(a.x); u.h[1] = f32_to_bf16(a.y);
  u.h[2] = f32_to_bf16(a.z); u.h[3] = f32_to_bf16(a.w);
  u.h[4] = f32_to_bf16(b.x); u.h[5] = f32_to_bf16(b.y);
  u.h[6] = f32_to_bf16(b.z); u.h[7] = f32_to_bf16(b.w);
  *(bf16x8*)(xb + i) = u.v;
}

// ---- Kernel 4: C = Xb(M x K) @ Wt(N x K)^T + bias ----
// 256x256 tile, BK=64 as 2 k-subtiles of 32. 8 waves in 2(M) x 4(N); per-wave 128x64
// = 8x4 frags of mfma_f32_16x16x32_bf16 (acc 128 VGPR).
//
// LDS (128 KiB): A area [0,32768) shorts, B area [32768,65536). Each operand has
// 4 slots (dbuf d in {0,1} x ksub s in {0,1}) of 16 KiB = [128 row-pairs][8 chunks
// of 16B]. Logical element (row r, kchunk kq in 0..3) lives at pair p=r>>1,
// chunk ch=(r&1)*4+kq, PHYSICAL chunk pch = ch ^ (p&7)  -> every ds_read_b128 is
// 2-way (free) on the 32 banks. XOR is an involution; staging writes LDS linearly
// (lane i at +i*16B) and gathers the inverse-swizzled GLOBAL chunk (rule 21).
//
// Pipeline (counted vmcnt, 2 phases per K-tile, 4 loads/thread/phase):
//   phase (t,0): stage (t+1,ks1); ds_read+MFMA ksub0; vmcnt(8); s_barrier
//   phase (t,1): stage (t+2,ks0); ds_read+MFMA ksub1; vmcnt(8); s_barrier
// Slot (t+1,ks1) was last read at phase (t-1,1) -> its stage issues after that
// barrier. Slot (t+2,ks0) was last read at (t,0) -> stage issues after (t,0)'s
// barrier. Every read of group g is covered by a vmcnt(8) with exactly the 8
// loads younger than g outstanding (2 phases of landing slack). Tail peels with
// vmcnt(8) -> vmcnt(4) -> vmcnt(0).
__global__ __launch_bounds__(512, 2) void gemm256_kernel(
    const unsigned short* __restrict__ Xb, const unsigned short* __restrict__ Wt,
    const float* __restrict__ bias, float* __restrict__ out) {
  __shared__ __align__(16) unsigned short lds[65536];  // 128 KiB

  const int tid = threadIdx.x;
  const int wave = tid >> 6, lane = tid & 63;
  const int quad = lane >> 4, lm = lane & 15;
  const int wm = wave >> 2, wn = wave & 3;  // 2 x 4 wave grid, per-wave 128(M) x 64(N)

  // T1: bijective XCD swizzle (grid 1024, 1024 % 8 == 0). Consecutive swz ids on one
  // XCD sweep N within an M-panel -> A-panel stays L2-resident.
  const int wg = blockIdx.x;
  const int swz = (wg & 7) * (1024 / 8) + (wg >> 3);
  const int m0 = (swz >> 4) * 256;  // 64 M-panels
  const int n0 = (swz & 15) * 256;  // 16 N-panels

  // Staging source (pre-swizzled gather). Thread tid owns LDS chunk (p = tid>>3,
  // pch = tid&7) of each 8 KiB issue; the global chunk living there is
  // ch = pch ^ (p&7) -> global row offset 2*(tid>>3) + (ch>>2), k offset (ch&3)*8.
  const int sch = (tid & 7) ^ ((tid >> 3) & 7);
  const int rowoff = 2 * (tid >> 3) + (sch >> 2);
  const int koff = (sch & 3) * 8;
  const unsigned short* srcA = Xb + (size_t)(m0 + rowoff) * K_TOT + koff;
  const unsigned short* srcB = Wt + (size_t)(n0 + rowoff) * K_TOT + koff;

  // Read-side swizzled offsets (shorts). Frag row r = base + 16*frag + lm:
  // p&7 == lm>>1, ch = (lm&1)*4 + quad -> pch is lane-constant across frags.
  const int pch = (((lm & 1) << 2) | quad) ^ (lm >> 1);
  const int aoff = wm * 4096 + (lm >> 1) * 64 + pch * 8;  // + i*512 per m-frag
  const int boff = wn * 2048 + (lm >> 1) * 64 + pch * 8;  // + j*512 per n-frag

  floatx4 acc[8][4];
#pragma unroll
  for (int i = 0; i < 8; ++i)
#pragma unroll
    for (int j = 0; j < 4; ++j) acc[i][j] = (floatx4){0.f, 0.f, 0.f, 0.f};

#define STAGE(tt, ss) do {                                                        \
    unsigned short* la = lds + ((((tt) & 1) * 2 + (ss)) * 8192) + tid * 8;        \
    size_t kk = (size_t)(tt) * 64 + (ss) * 32;                                    \
    async_copy16(srcA + kk, la);                                                  \
    async_copy16(srcA + kk + (size_t)128 * K_TOT, la + 4096);                     \
    async_copy16(srcB + kk, la + 32768);                                          \
    async_copy16(srcB + kk + (size_t)128 * K_TOT, la + 32768 + 4096);             \
  } while (0)

#define COMPUTE(tt, ss) do {                                                      \
    const unsigned short* Ab = lds + ((((tt) & 1) * 2 + (ss)) * 8192) + aoff;     \
    const unsigned short* Bb = lds + 32768 + ((((tt) & 1) * 2 + (ss)) * 8192) + boff; \
    bf16x8 af[8], bfr[4];                                                         \
    _Pragma("unroll") for (int i = 0; i < 8; ++i)                                 \
      af[i] = *(const bf16x8*)(Ab + i * 512);                                     \
    _Pragma("unroll") for (int j = 0; j < 4; ++j)                                 \
      bfr[j] = *(const bf16x8*)(Bb + j * 512);                                    \
    __builtin_amdgcn_s_setprio(1);                                                \
    _Pragma("unroll") for (int i = 0; i < 8; ++i)                                 \
      _Pragma("unroll") for (int j = 0; j < 4; ++j)                               \
        acc[i][j] = __builtin_amdgcn_mfma_f32_16x16x32_bf16(af[i], bfr[j], acc[i][j], 0, 0, 0); \
    __builtin_amdgcn_s_setprio(0);                                                \
  } while (0)

// Counted-vmcnt wait + barrier, with memory fences on BOTH sides of s_barrier:
// the trailing empty asm pins later ds_reads below the barrier (LLVM does not
// treat s_barrier as a memory fence -- without it a read of the just-staged slot
// could hoist above the barrier and race other waves' still-in-flight loads).
#define WAITBAR(n) do {                                                          \
    asm volatile("s_waitcnt vmcnt(" #n ")" ::: "memory");                        \
    __builtin_amdgcn_s_barrier();                                                \
    asm volatile("" ::: "memory");                                               \
  } while (0)

  // Prologue: stream = [(0,ks0),(0,ks1),(1,ks0)]; need (0,ks0) landed -> 8 younger.
  STAGE(0, 0);
  STAGE(0, 1);
  STAGE(1, 0);
  WAITBAR(8);

  for (int t = 0; t < NT - 2; ++t) {
    STAGE(t + 1, 1);
    COMPUTE(t, 0);
    WAITBAR(8);
    STAGE(t + 2, 0);
    COMPUTE(t, 1);
    WAITBAR(8);
  }
  // t = NT-2: only (NT-1,ks1) left to stage.
  STAGE(NT - 1, 1);
  COMPUTE(NT - 2, 0);
  WAITBAR(8);
  COMPUTE(NT - 2, 1);
  WAITBAR(4);  // need (NT-1,ks0); only (NT-1,ks1)'s 4 loads are younger
  // t = NT-1: nothing to stage.
  COMPUTE(NT - 1, 0);
  WAITBAR(0);  // need (NT-1,ks1); nothing younger
  COMPUTE(NT - 1, 1);

#undef STAGE
#undef COMPUTE
#undef WAITBAR

  // Epilogue: C/D layout col = lane&15, row = quad*4 + reg. Fuse bias.
#pragma unroll
  for (int j = 0; j < 4; ++j) {
    int col = n0 + wn * 64 + j * 16 + lm;
    float bv = bias[col];
#pragma unroll
    for (int i = 0; i < 8; ++i) {
      int row = m0 + wm * 128 + i * 16 + quad * 4;
#pragma unroll
      for (int r = 0; r < 4; ++r)
        out[(size_t)(row + r) * N_TOT + col] = acc[i][j][r] + bv;
    }
  }
}

extern "C" void kernel_launch(void* const* d_in, const int* in_sizes, int n_in,
                              void* d_out, int out_size, void* d_ws, size_t ws_size,
                              hipStream_t stream) {
  const float* x    = (const float*)d_in[0];  // (4,4096,4096) -> M=16384, K=4096
  const float* base = (const float*)d_in[1];  // (4096,4096) K x N
  const float* bias = (const float*)d_in[2];  // (4096,)
  const float* lA   = (const float*)d_in[3];  // (16,16)
  const float* lB   = (const float*)d_in[4];  // (16,16)
  const float* O    = (const float*)d_in[5];  // (256,256)
  float* out = (float*)d_out;

  // Workspace layout: Xb bf16 (128 MB) | Wt bf16 (32 MB) | wl f32 (1 KB)
  char* ws = (char*)d_ws;
  unsigned short* Xb = (unsigned short*)ws;
  unsigned short* Wt = (unsigned short*)(ws + (size_t)M_TOT * K_TOT * 2);
  float* wl = (float*)(ws + (size_t)M_TOT * K_TOT * 2 + (size_t)N_TOT * K_TOT * 2);

  wleft_kernel<<<1, 256, 0, stream>>>(lA, lB, wl);
  prep_w_kernel<<<dim3(N_TOT / 32, K_TOT / 32), dim3(32, 8), 0, stream>>>(base, O, wl, Wt);
  cvt_x_kernel<<<((size_t)M_TOT * K_TOT) / 8 / 256, 256, 0, stream>>>(x, Xb);
  gemm256_kernel<<<dim3(1024), 512, 0, stream>>>(Xb, Wt, bias, out);
}